// Round 3
// baseline (1136.223 us; speedup 1.0000x reference)
//
#include <hip/hip_runtime.h>
#include <stdint.h>
#include <math.h>

// Problem constants
constexpr int Bb = 8, Tt = 512, Hh = 2048, Vv = 32000;
constexpr int M = Bb * Tt;     // 4096 tokens
constexpr int K = Hh;          // 2048
constexpr int N = Vv;          // 32000 vocab
constexpr int NB = N / 128;    // 250 column blocks
constexpr int KITERS = K / 64; // 32
constexpr int IGNORE = -100;

typedef __attribute__((ext_vector_type(8))) short bf16x8;
typedef __attribute__((ext_vector_type(4))) float f32x4;

__device__ inline void gld16(const void* g, const void* l) {
  __builtin_amdgcn_global_load_lds(
      (const __attribute__((address_space(1))) uint32_t*)g,
      (__attribute__((address_space(3))) uint32_t*)l, 16, 0, 0);
}

__device__ inline unsigned short f2bf(float f) {
  union { float f; unsigned u; } x; x.f = f;
  unsigned r = x.u + 0x7fffu + ((x.u >> 16) & 1u);  // RNE
  return (unsigned short)(r >> 16);
}

// ---------------- cast fp32 -> bf16, vectorized ----------------
__global__ void cast_bf16_kernel(const float* __restrict__ src,
                                 unsigned short* __restrict__ dst, int n4) {
  int i = blockIdx.x * blockDim.x + threadIdx.x;
  int stride = gridDim.x * blockDim.x;
  const float4* s4 = (const float4*)src;
  ushort4* d4 = (ushort4*)dst;
  for (; i < n4; i += stride) {
    float4 v = s4[i];
    ushort4 o;
    o.x = f2bf(v.x); o.y = f2bf(v.y); o.z = f2bf(v.z); o.w = f2bf(v.w);
    d4[i] = o;
  }
}

// ---------------- GEMM + fused per-row softmax-stats epilogue ----------------
// C[m][n] = sum_k X[m][k]*W[n][k] + bias[n]; per 128x128 tile emit per-row
// partial (max, sumexp) and scatter logit where n == target[m].
//
// LDS is XOR-swizzled at 16B granularity (chunk j of row r at slot j^(r&7)),
// applied on the GLOBAL source address at staging (bank-conflict-free reads,
// verified: SQ_LDS_BANK_CONFLICT dropped 1.97e8 -> 0).
//
// Double-buffered: barrier -> prefetch(next tile -> other buf) -> compute.
// The prefetch has a full compute phase in flight before the next barrier's
// vmcnt(0) drain, hiding the L3-class W-load latency (the R2 ~40% stall).
__global__ __launch_bounds__(256)
void gemm_stats(const unsigned short* __restrict__ X,
                const unsigned short* __restrict__ W,
                const float* __restrict__ bias,
                const int* __restrict__ tgt,
                float* __restrict__ m_part,
                float* __restrict__ s_part,
                float* __restrict__ tlogit) {
  __shared__ __align__(16) unsigned short As[2][128 * 64];  // 32 KB
  __shared__ __align__(16) unsigned short Bs[2][128 * 64];  // 32 KB
  __shared__ float red_m[2][128];
  __shared__ float red_s[2][128];

  const int tid = threadIdx.x;
  const int lane = tid & 63;
  const int wid = tid >> 6;          // 4 waves
  const int waveM = wid >> 1;        // 2x2 wave grid, each wave 64x64
  const int waveN = wid & 1;
  const int q = lane >> 4;           // quad 0..3
  const int c = lane & 15;
  const int bm = blockIdx.x;         // 0..31  (m fastest -> weight streams ~once)
  const int bn = blockIdx.y;         // 0..249

  // staging: each wave loads 32 rows of A-tile and 32 rows of B-tile.
  const int srow = lane >> 3;                       // 0..7
  const int scol = ((lane & 7) ^ srow) * 8;         // swizzled 16B chunk
  const unsigned short* gA = X + (size_t)(bm * 128 + wid * 32 + srow) * K + scol;
  const unsigned short* gB = W + (size_t)(bn * 128 + wid * 32 + srow) * K + scol;
  const int ldsRow = wid * 32 + srow;

  f32x4 acc[4][4];
#pragma unroll
  for (int i = 0; i < 4; ++i)
#pragma unroll
    for (int j = 0; j < 4; ++j) acc[i][j] = (f32x4){0.f, 0.f, 0.f, 0.f};

  // prologue: stage tile 0 into buffer 0
#pragma unroll
  for (int j = 0; j < 4; ++j) {
    gld16(gA + (size_t)j * 8 * K, &As[0][(ldsRow + j * 8) * 64]);
    gld16(gB + (size_t)j * 8 * K, &Bs[0][(ldsRow + j * 8) * 64]);
  }

  for (int it = 0; it < KITERS; ++it) {
    const int cur = it & 1;
    __syncthreads();  // drains the prefetch into buf[cur] (in flight ~1 iter)

    if (it + 1 < KITERS) {
      const int k0 = (it + 1) * 64;
#pragma unroll
      for (int j = 0; j < 4; ++j) {
        gld16(gA + (size_t)j * 8 * K + k0, &As[cur ^ 1][(ldsRow + j * 8) * 64]);
        gld16(gB + (size_t)j * 8 * K + k0, &Bs[cur ^ 1][(ldsRow + j * 8) * 64]);
      }
    }

#pragma unroll
    for (int kk = 0; kk < 2; ++kk) {
      bf16x8 af[4], bfr[4];
#pragma unroll
      for (int i = 0; i < 4; ++i) {
        const int rA = waveM * 64 + i * 16 + c;
        const int rB = waveN * 64 + i * 16 + c;
        const int chunk = kk * 4 + q;
        af[i]  = *(const bf16x8*)(&As[cur][rA * 64 + ((chunk ^ (rA & 7)) * 8)]);
        bfr[i] = *(const bf16x8*)(&Bs[cur][rB * 64 + ((chunk ^ (rB & 7)) * 8)]);
      }
#pragma unroll
      for (int mi = 0; mi < 4; ++mi)
#pragma unroll
        for (int ni = 0; ni < 4; ++ni)
          acc[mi][ni] = __builtin_amdgcn_mfma_f32_16x16x32_bf16(
              af[mi], bfr[ni], acc[mi][ni], 0, 0, 0);
    }
  }

  // ---- epilogue: per-row (max, sumexp) over this block's 128 columns ----
  const int colBase = bn * 128 + waveN * 64;
  float bvals[4];
#pragma unroll
  for (int ni = 0; ni < 4; ++ni) bvals[ni] = bias[colBase + ni * 16 + c];

#pragma unroll
  for (int mi = 0; mi < 4; ++mi) {
    const int rowBase = bm * 128 + waveM * 64 + mi * 16 + q * 4;
#pragma unroll
    for (int reg = 0; reg < 4; ++reg) {
      const int grow = rowBase + reg;
      const int t = tgt[grow];
      float v[4];
      float mloc = -3.4e38f;
#pragma unroll
      for (int ni = 0; ni < 4; ++ni) {
        v[ni] = acc[mi][ni][reg] + bvals[ni];
        mloc = fmaxf(mloc, v[ni]);
        const int gn = colBase + ni * 16 + c;
        if (gn == t) tlogit[grow] = v[ni];  // exactly one lane/block matches
      }
#pragma unroll
      for (int off = 1; off < 16; off <<= 1) mloc = fmaxf(mloc, __shfl_xor(mloc, off));
      float sloc = 0.f;
#pragma unroll
      for (int ni = 0; ni < 4; ++ni) sloc += __expf(v[ni] - mloc);
#pragma unroll
      for (int off = 1; off < 16; off <<= 1) sloc += __shfl_xor(sloc, off);
      if (c == 0) {
        const int lrow = waveM * 64 + mi * 16 + q * 4 + reg;
        red_m[waveN][lrow] = mloc;
        red_s[waveN][lrow] = sloc;
      }
    }
  }
  __syncthreads();
  if (tid < 128) {
    const float m0 = red_m[0][tid], m1 = red_m[1][tid];
    const float s0 = red_s[0][tid], s1 = red_s[1][tid];
    const float mx = fmaxf(m0, m1);
    const float ss = s0 * __expf(m0 - mx) + s1 * __expf(m1 - mx);
    const int grow = bm * 128 + tid;
    m_part[(size_t)grow * NB + bn] = mx;
    s_part[(size_t)grow * NB + bn] = ss;
  }
}

// ---------------- combine per-row partials -> per-token logp ----------------
__global__ __launch_bounds__(256)
void combine_rows(const float* __restrict__ m_part, const float* __restrict__ s_part,
                  const float* __restrict__ tlogit, const int* __restrict__ tgt,
                  float* __restrict__ logp) {
  const int row = blockIdx.x * 4 + (threadIdx.x >> 6);
  const int lane = threadIdx.x & 63;
  const float* mrow = m_part + (size_t)row * NB;
  const float* srow = s_part + (size_t)row * NB;
  float mv[4], sv[4];
  int cnt = 0;
  float mx = -3.4e38f;
  for (int cc = lane; cc < NB; cc += 64) {
    mv[cnt] = mrow[cc]; sv[cnt] = srow[cc];
    mx = fmaxf(mx, mv[cnt]); ++cnt;
  }
#pragma unroll
  for (int off = 32; off >= 1; off >>= 1) mx = fmaxf(mx, __shfl_xor(mx, off));
  float s = 0.f;
  for (int i = 0; i < cnt; ++i) s += sv[i] * __expf(mv[i] - mx);
#pragma unroll
  for (int off = 32; off >= 1; off >>= 1) s += __shfl_xor(s, off);
  if (lane == 0) {
    const int t = tgt[row];
    logp[row] = (t == IGNORE) ? 0.f : (tlogit[row] - mx - logf(s));
  }
}

// ---------------- per-sequence average + SimPO loss ----------------
__global__ void finalize(const float* __restrict__ logp, const int* __restrict__ tgt,
                         float* __restrict__ out) {
  __shared__ float avg[8];
  const int w = threadIdx.x >> 6;     // 8 waves, one per sequence
  const int lane = threadIdx.x & 63;
  float s = 0.f, cnt = 0.f;
  for (int i = lane; i < Tt; i += 64) {
    const int idx = w * Tt + i;
    s += logp[idx];
    cnt += (tgt[idx] != IGNORE) ? 1.f : 0.f;
  }
#pragma unroll
  for (int off = 32; off >= 1; off >>= 1) {
    s += __shfl_xor(s, off);
    cnt += __shfl_xor(cnt, off);
  }
  if (lane == 0) avg[w] = s / fmaxf(cnt, 1.f);
  __syncthreads();
  if (threadIdx.x == 0) {
    float loss = 0.f;
#pragma unroll
    for (int p = 0; p < 4; ++p) {
      const float d = 0.1f * (avg[p] - avg[p + 4]) - 0.5f;
      const float nl = (d > 0.f) ? log1pf(expf(-d)) : (-d + log1pf(expf(d)));
      loss += nl;
    }
    out[0] = loss * 0.25f;  // / n_pairs
  }
}

extern "C" void kernel_launch(void* const* d_in, const int* in_sizes, int n_in,
                              void* d_out, int out_size, void* d_ws, size_t ws_size,
                              hipStream_t stream) {
  const float* Wf   = (const float*)d_in[0];  // lin_weight (V,H)
  const float* Xf   = (const float*)d_in[1];  // _input (B,T,H)
  const int*   tgt  = (const int*)d_in[2];    // target (B,T)
  const float* bias = (const float*)d_in[3];  // bias (V,)
  float* out = (float*)d_out;

  char* ws = (char*)d_ws;
  size_t off = 0;
  auto alloc = [&](size_t bytes) {
    void* p = ws + off;
    off += (bytes + 255) & ~(size_t)255;
    return p;
  };
  unsigned short* Xbf = (unsigned short*)alloc((size_t)M * K * 2);
  unsigned short* Wbf = (unsigned short*)alloc((size_t)N * K * 2);
  float* m_part = (float*)alloc((size_t)M * NB * 4);
  float* s_part = (float*)alloc((size_t)M * NB * 4);
  float* tlog   = (float*)alloc((size_t)M * 4);
  float* logp   = (float*)alloc((size_t)M * 4);

  cast_bf16_kernel<<<2048, 256, 0, stream>>>(Xf, Xbf, M * K / 4);
  cast_bf16_kernel<<<8192, 256, 0, stream>>>(Wf, Wbf, N * K / 4);

  dim3 grid(M / 128, NB);  // 32 x 250; m fastest for weight-stream L2/L3 reuse
  gemm_stats<<<grid, 256, 0, stream>>>(Xbf, Wbf, bias, tgt, m_part, s_part, tlog);

  combine_rows<<<M / 4, 256, 0, stream>>>(m_part, s_part, tlog, tgt, logp);
  finalize<<<1, 512, 0, stream>>>(logp, tgt, out);
}

// Round 4
// 1042.207 us; speedup vs baseline: 1.0902x; 1.0902x over previous
//
#include <hip/hip_runtime.h>
#include <stdint.h>
#include <math.h>

// Problem constants
constexpr int Bb = 8, Tt = 512, Hh = 2048, Vv = 32000;
constexpr int M = Bb * Tt;     // 4096 tokens
constexpr int K = Hh;          // 2048
constexpr int N = Vv;          // 32000 vocab
constexpr int NB = N / 128;    // 250 column blocks
constexpr int KITERS = K / 64; // 32 (even)
constexpr int IGNORE = -100;

typedef __attribute__((ext_vector_type(8))) short bf16x8;
typedef __attribute__((ext_vector_type(4))) float f32x4;

__device__ inline void gld16(const void* g, const void* l) {
  __builtin_amdgcn_global_load_lds(
      (const __attribute__((address_space(1))) uint32_t*)g,
      (__attribute__((address_space(3))) uint32_t*)l, 16, 0, 0);
}

__device__ inline unsigned short f2bf(float f) {
  union { float f; unsigned u; } x; x.f = f;
  unsigned r = x.u + 0x7fffu + ((x.u >> 16) & 1u);  // RNE
  return (unsigned short)(r >> 16);
}

// ---------------- cast fp32 -> bf16, vectorized ----------------
__global__ void cast_bf16_kernel(const float* __restrict__ src,
                                 unsigned short* __restrict__ dst, int n4) {
  int i = blockIdx.x * blockDim.x + threadIdx.x;
  int stride = gridDim.x * blockDim.x;
  const float4* s4 = (const float4*)src;
  ushort4* d4 = (ushort4*)dst;
  for (; i < n4; i += stride) {
    float4 v = s4[i];
    ushort4 o;
    o.x = f2bf(v.x); o.y = f2bf(v.y); o.z = f2bf(v.z); o.w = f2bf(v.w);
    d4[i] = o;
  }
}

// ---------------- GEMM + fused per-row softmax-stats epilogue ----------------
// C[m][n] = sum_k X[m][k]*W[n][k] + bias[n]; per 128x128 tile emit per-row
// partial (max, sumexp) and scatter logit where n == target[m].
//
// LDS XOR-swizzled at 16B granularity (chunk j of row r at slot j^(r&7)),
// applied on the GLOBAL source address at staging (R2-verified: conflicts
// 1.97e8 -> 0).
//
// Double-buffered with STATIC buffer identity (2x manual unroll): even tiles
// in buf0, odd in buf1. Schedule per half-iter:
//   barrier(drains prefetch issued one half-iter ago, covered by compute)
//   -> issue prefetch(next tile -> other buf) -> compute(cur buf).
// All fragment offsets are loop-invariant (R3's dynamic [cur] indexing
// caused VALUBusy 26%->41% and a net regression).
__global__ __launch_bounds__(256)
void gemm_stats(const unsigned short* __restrict__ X,
                const unsigned short* __restrict__ W,
                const float* __restrict__ bias,
                const int* __restrict__ tgt,
                float* __restrict__ m_part,
                float* __restrict__ s_part,
                float* __restrict__ tlogit) {
  __shared__ __align__(16) unsigned short As0[128 * 64];
  __shared__ __align__(16) unsigned short As1[128 * 64];
  __shared__ __align__(16) unsigned short Bs0[128 * 64];
  __shared__ __align__(16) unsigned short Bs1[128 * 64];
  __shared__ float red_m[2][128];
  __shared__ float red_s[2][128];

  const int tid = threadIdx.x;
  const int lane = tid & 63;
  const int wid = tid >> 6;          // 4 waves
  const int waveM = wid >> 1;        // 2x2 wave grid, each wave 64x64
  const int waveN = wid & 1;
  const int q = lane >> 4;           // quad 0..3
  const int c = lane & 15;
  const int bm = blockIdx.x;         // 0..31  (m fastest -> weight streams ~once)
  const int bn = blockIdx.y;         // 0..249

  // staging: each wave loads 32 rows of A-tile and 32 rows of B-tile.
  const int srow = lane >> 3;                       // 0..7
  const int scol = ((lane & 7) ^ srow) * 8;         // swizzled 16B chunk
  const unsigned short* gA = X + (size_t)(bm * 128 + wid * 32 + srow) * K + scol;
  const unsigned short* gB = W + (size_t)(bn * 128 + wid * 32 + srow) * K + scol;
  const int ldsRow = wid * 32 + srow;

  // loop-invariant fragment element offsets within a 128x64 tile
  int offA[2][4], offB[2][4];
#pragma unroll
  for (int kk = 0; kk < 2; ++kk)
#pragma unroll
    for (int i = 0; i < 4; ++i) {
      const int rA = waveM * 64 + i * 16 + c;
      const int rB = waveN * 64 + i * 16 + c;
      const int chunk = kk * 4 + q;
      offA[kk][i] = rA * 64 + ((chunk ^ (rA & 7)) * 8);
      offB[kk][i] = rB * 64 + ((chunk ^ (rB & 7)) * 8);
    }

  f32x4 acc[4][4];
#pragma unroll
  for (int i = 0; i < 4; ++i)
#pragma unroll
    for (int j = 0; j < 4; ++j) acc[i][j] = (f32x4){0.f, 0.f, 0.f, 0.f};

  auto stage = [&](unsigned short* Ad, unsigned short* Bd, int tile) {
    const size_t k0 = (size_t)tile * 64;
#pragma unroll
    for (int j = 0; j < 4; ++j) {
      gld16(gA + (size_t)j * 8 * K + k0, Ad + (ldsRow + j * 8) * 64);
      gld16(gB + (size_t)j * 8 * K + k0, Bd + (ldsRow + j * 8) * 64);
    }
  };
  auto compute = [&](const unsigned short* Asb, const unsigned short* Bsb) {
#pragma unroll
    for (int kk = 0; kk < 2; ++kk) {
      bf16x8 af[4], bfr[4];
#pragma unroll
      for (int i = 0; i < 4; ++i) {
        af[i]  = *(const bf16x8*)(Asb + offA[kk][i]);
        bfr[i] = *(const bf16x8*)(Bsb + offB[kk][i]);
      }
#pragma unroll
      for (int mi = 0; mi < 4; ++mi)
#pragma unroll
        for (int ni = 0; ni < 4; ++ni)
          acc[mi][ni] = __builtin_amdgcn_mfma_f32_16x16x32_bf16(
              af[mi], bfr[ni], acc[mi][ni], 0, 0, 0);
    }
  };

  // prologue: tile 0 -> buf0
  stage(As0, Bs0, 0);

  for (int i2 = 0; i2 < KITERS / 2 - 1; ++i2) {
    __syncthreads();                 // drain buf0 prefetch (tile 2*i2)
    stage(As1, Bs1, 2 * i2 + 1);     // -> buf1
    compute(As0, Bs0);               // tile 2*i2
    __syncthreads();                 // drain buf1 prefetch (tile 2*i2+1)
    stage(As0, Bs0, 2 * i2 + 2);     // -> buf0
    compute(As1, Bs1);               // tile 2*i2+1
  }
  // tail: tiles 30 (buf0) and 31 (buf1)
  __syncthreads();
  stage(As1, Bs1, KITERS - 1);
  compute(As0, Bs0);
  __syncthreads();
  compute(As1, Bs1);

  // ---- epilogue: per-row (max, sumexp) over this block's 128 columns ----
  const int colBase = bn * 128 + waveN * 64;
  float bvals[4];
#pragma unroll
  for (int ni = 0; ni < 4; ++ni) bvals[ni] = bias[colBase + ni * 16 + c];

#pragma unroll
  for (int mi = 0; mi < 4; ++mi) {
    const int rowBase = bm * 128 + waveM * 64 + mi * 16 + q * 4;
#pragma unroll
    for (int reg = 0; reg < 4; ++reg) {
      const int grow = rowBase + reg;
      const int t = tgt[grow];
      float v[4];
      float mloc = -3.4e38f;
#pragma unroll
      for (int ni = 0; ni < 4; ++ni) {
        v[ni] = acc[mi][ni][reg] + bvals[ni];
        mloc = fmaxf(mloc, v[ni]);
        const int gn = colBase + ni * 16 + c;
        if (gn == t) tlogit[grow] = v[ni];  // exactly one lane/block matches
      }
#pragma unroll
      for (int off = 1; off < 16; off <<= 1) mloc = fmaxf(mloc, __shfl_xor(mloc, off));
      float sloc = 0.f;
#pragma unroll
      for (int ni = 0; ni < 4; ++ni) sloc += __expf(v[ni] - mloc);
#pragma unroll
      for (int off = 1; off < 16; off <<= 1) sloc += __shfl_xor(sloc, off);
      if (c == 0) {
        const int lrow = waveM * 64 + mi * 16 + q * 4 + reg;
        red_m[waveN][lrow] = mloc;
        red_s[waveN][lrow] = sloc;
      }
    }
  }
  __syncthreads();
  if (tid < 128) {
    const float m0 = red_m[0][tid], m1 = red_m[1][tid];
    const float s0 = red_s[0][tid], s1 = red_s[1][tid];
    const float mx = fmaxf(m0, m1);
    const float ss = s0 * __expf(m0 - mx) + s1 * __expf(m1 - mx);
    const int grow = bm * 128 + tid;
    m_part[(size_t)grow * NB + bn] = mx;
    s_part[(size_t)grow * NB + bn] = ss;
  }
}

// ---------------- combine per-row partials -> per-token logp ----------------
__global__ __launch_bounds__(256)
void combine_rows(const float* __restrict__ m_part, const float* __restrict__ s_part,
                  const float* __restrict__ tlogit, const int* __restrict__ tgt,
                  float* __restrict__ logp) {
  const int row = blockIdx.x * 4 + (threadIdx.x >> 6);
  const int lane = threadIdx.x & 63;
  const float* mrow = m_part + (size_t)row * NB;
  const float* srow = s_part + (size_t)row * NB;
  float mv[4], sv[4];
  int cnt = 0;
  float mx = -3.4e38f;
  for (int cc = lane; cc < NB; cc += 64) {
    mv[cnt] = mrow[cc]; sv[cnt] = srow[cc];
    mx = fmaxf(mx, mv[cnt]); ++cnt;
  }
#pragma unroll
  for (int off = 32; off >= 1; off >>= 1) mx = fmaxf(mx, __shfl_xor(mx, off));
  float s = 0.f;
  for (int i = 0; i < cnt; ++i) s += sv[i] * __expf(mv[i] - mx);
#pragma unroll
  for (int off = 32; off >= 1; off >>= 1) s += __shfl_xor(s, off);
  if (lane == 0) {
    const int t = tgt[row];
    logp[row] = (t == IGNORE) ? 0.f : (tlogit[row] - mx - logf(s));
  }
}

// ---------------- per-sequence average + SimPO loss ----------------
__global__ void finalize(const float* __restrict__ logp, const int* __restrict__ tgt,
                         float* __restrict__ out) {
  __shared__ float avg[8];
  const int w = threadIdx.x >> 6;     // 8 waves, one per sequence
  const int lane = threadIdx.x & 63;
  float s = 0.f, cnt = 0.f;
  for (int i = lane; i < Tt; i += 64) {
    const int idx = w * Tt + i;
    s += logp[idx];
    cnt += (tgt[idx] != IGNORE) ? 1.f : 0.f;
  }
#pragma unroll
  for (int off = 32; off >= 1; off >>= 1) {
    s += __shfl_xor(s, off);
    cnt += __shfl_xor(cnt, off);
  }
  if (lane == 0) avg[w] = s / fmaxf(cnt, 1.f);
  __syncthreads();
  if (threadIdx.x == 0) {
    float loss = 0.f;
#pragma unroll
    for (int p = 0; p < 4; ++p) {
      const float d = 0.1f * (avg[p] - avg[p + 4]) - 0.5f;
      const float nl = (d > 0.f) ? log1pf(expf(-d)) : (-d + log1pf(expf(d)));
      loss += nl;
    }
    out[0] = loss * 0.25f;  // / n_pairs
  }
}

extern "C" void kernel_launch(void* const* d_in, const int* in_sizes, int n_in,
                              void* d_out, int out_size, void* d_ws, size_t ws_size,
                              hipStream_t stream) {
  const float* Wf   = (const float*)d_in[0];  // lin_weight (V,H)
  const float* Xf   = (const float*)d_in[1];  // _input (B,T,H)
  const int*   tgt  = (const int*)d_in[2];    // target (B,T)
  const float* bias = (const float*)d_in[3];  // bias (V,)
  float* out = (float*)d_out;

  char* ws = (char*)d_ws;
  size_t off = 0;
  auto alloc = [&](size_t bytes) {
    void* p = ws + off;
    off += (bytes + 255) & ~(size_t)255;
    return p;
  };
  unsigned short* Xbf = (unsigned short*)alloc((size_t)M * K * 2);
  unsigned short* Wbf = (unsigned short*)alloc((size_t)N * K * 2);
  float* m_part = (float*)alloc((size_t)M * NB * 4);
  float* s_part = (float*)alloc((size_t)M * NB * 4);
  float* tlog   = (float*)alloc((size_t)M * 4);
  float* logp   = (float*)alloc((size_t)M * 4);

  cast_bf16_kernel<<<2048, 256, 0, stream>>>(Xf, Xbf, M * K / 4);
  cast_bf16_kernel<<<8192, 256, 0, stream>>>(Wf, Wbf, N * K / 4);

  dim3 grid(M / 128, NB);  // 32 x 250; m fastest for weight-stream L2/L3 reuse
  gemm_stats<<<grid, 256, 0, stream>>>(Xbf, Wbf, bias, tgt, m_part, s_part, tlog);

  combine_rows<<<M / 4, 256, 0, stream>>>(m_part, s_part, tlog, tgt, logp);
  finalize<<<1, 512, 0, stream>>>(logp, tgt, out);
}

// Round 5
// 1000.143 us; speedup vs baseline: 1.1361x; 1.0421x over previous
//
#include <hip/hip_runtime.h>
#include <stdint.h>
#include <math.h>

// Problem constants
constexpr int Bb = 8, Tt = 512, Hh = 2048, Vv = 32000;
constexpr int M = Bb * Tt;     // 4096 tokens
constexpr int K = Hh;          // 2048
constexpr int N = Vv;          // 32000 vocab
constexpr int NB = N / 128;    // 250 column blocks
constexpr int BK = 32;         // K-tile depth
constexpr int KITERS = K / BK; // 64 (even)
constexpr int IGNORE = -100;

typedef __attribute__((ext_vector_type(8))) short bf16x8;
typedef __attribute__((ext_vector_type(4))) float f32x4;

__device__ inline void gld16(const void* g, const void* l) {
  __builtin_amdgcn_global_load_lds(
      (const __attribute__((address_space(1))) uint32_t*)g,
      (__attribute__((address_space(3))) uint32_t*)l, 16, 0, 0);
}

__device__ inline unsigned short f2bf(float f) {
  union { float f; unsigned u; } x; x.f = f;
  unsigned r = x.u + 0x7fffu + ((x.u >> 16) & 1u);  // RNE
  return (unsigned short)(r >> 16);
}

// ---------------- cast fp32 -> bf16, vectorized ----------------
__global__ void cast_bf16_kernel(const float* __restrict__ src,
                                 unsigned short* __restrict__ dst, int n4) {
  int i = blockIdx.x * blockDim.x + threadIdx.x;
  int stride = gridDim.x * blockDim.x;
  const float4* s4 = (const float4*)src;
  ushort4* d4 = (ushort4*)dst;
  for (; i < n4; i += stride) {
    float4 v = s4[i];
    ushort4 o;
    o.x = f2bf(v.x); o.y = f2bf(v.y); o.z = f2bf(v.z); o.w = f2bf(v.w);
    d4[i] = o;
  }
}

// ---------------- GEMM + fused per-row softmax-stats epilogue ----------------
// C[m][n] = sum_k X[m][k]*W[n][k] + bias[n]; per 128x128 tile emit per-row
// partial (max, sumexp) and scatter logit where n == target[m].
//
// BK=32 double-buffer with static buffer identity: LDS = 4 x 8 KB + 2 KB
// reductions = 34 KB -> 4 blocks/CU (R4's 67.5 KB capped at 2 blocks/CU and
// the barrier phase-lock serialized the ds_read and MFMA pipes: measured
// LDS 0.77 Mcyc + MFMA 0.62 Mcyc ~= 82% of the 1.7 Mcyc total, i.e. almost
// no pipe overlap). 4 independent blocks/CU restore phase diversity.
//
// LDS rows are 64 B (32 bf16). Swizzle: 16B-chunk q of row r lives at slot
// q^(r&3) -> fragment reads are conflict-free (16 lanes/quad span 32 banks,
// 2 lanes/bank = free). Applied on the GLOBAL source address at staging;
// there it reduces to the loop-invariant (lane&3)^((lane>>2)&3).
__global__ __launch_bounds__(256, 4)
void gemm_stats(const unsigned short* __restrict__ X,
                const unsigned short* __restrict__ W,
                const float* __restrict__ bias,
                const int* __restrict__ tgt,
                float* __restrict__ m_part,
                float* __restrict__ s_part,
                float* __restrict__ tlogit) {
  __shared__ __align__(16) unsigned short As0[128 * BK];  // 8 KB each
  __shared__ __align__(16) unsigned short As1[128 * BK];
  __shared__ __align__(16) unsigned short Bs0[128 * BK];
  __shared__ __align__(16) unsigned short Bs1[128 * BK];
  __shared__ float red_m[2][128];
  __shared__ float red_s[2][128];

  const int tid = threadIdx.x;
  const int lane = tid & 63;
  const int wid = tid >> 6;          // 4 waves
  const int waveM = wid >> 1;        // 2x2 wave grid, each wave 64x64
  const int waveN = wid & 1;
  const int q = lane >> 4;           // quad 0..3
  const int c = lane & 15;
  const int bm = blockIdx.x;         // 0..31  (m fastest -> weight streams ~once)
  const int bn = blockIdx.y;         // 0..249

  // staging: 4 lanes per 64B row; round j covers rows j*64..j*64+63.
  const int strow = tid >> 2;                            // 0..63
  const int schunk = (lane & 3) ^ ((lane >> 2) & 3);     // swizzled 16B chunk
  const unsigned short* gA = X + (size_t)(bm * 128 + strow) * K + schunk * 8;
  const unsigned short* gB = W + (size_t)(bn * 128 + strow) * K + schunk * 8;
  const int dRow = wid * 16;  // wave-uniform LDS dest row within a round

  // loop-invariant fragment element offsets within a 128x32 tile
  int offA[4], offB[4];
#pragma unroll
  for (int i = 0; i < 4; ++i) {
    const int rA = waveM * 64 + i * 16 + c;
    const int rB = waveN * 64 + i * 16 + c;
    offA[i] = rA * BK + ((q ^ (rA & 3)) * 8);
    offB[i] = rB * BK + ((q ^ (rB & 3)) * 8);
  }

  f32x4 acc[4][4];
#pragma unroll
  for (int i = 0; i < 4; ++i)
#pragma unroll
    for (int j = 0; j < 4; ++j) acc[i][j] = (f32x4){0.f, 0.f, 0.f, 0.f};

  auto stage = [&](unsigned short* Ad, unsigned short* Bd, int tile) {
    const size_t k0 = (size_t)tile * BK;
#pragma unroll
    for (int j = 0; j < 2; ++j) {
      gld16(gA + (size_t)j * 64 * K + k0, Ad + (j * 64 + dRow) * BK);
      gld16(gB + (size_t)j * 64 * K + k0, Bd + (j * 64 + dRow) * BK);
    }
  };
  auto compute = [&](const unsigned short* Asb, const unsigned short* Bsb) {
    bf16x8 af[4], bfr[4];
#pragma unroll
    for (int i = 0; i < 4; ++i) {
      af[i]  = *(const bf16x8*)(Asb + offA[i]);
      bfr[i] = *(const bf16x8*)(Bsb + offB[i]);
    }
#pragma unroll
    for (int mi = 0; mi < 4; ++mi)
#pragma unroll
      for (int ni = 0; ni < 4; ++ni)
        acc[mi][ni] = __builtin_amdgcn_mfma_f32_16x16x32_bf16(
            af[mi], bfr[ni], acc[mi][ni], 0, 0, 0);
  };

  // prologue: tile 0 -> buf0
  stage(As0, Bs0, 0);

  for (int i2 = 0; i2 < KITERS / 2 - 1; ++i2) {
    __syncthreads();                 // drain buf0 prefetch
    stage(As1, Bs1, 2 * i2 + 1);     // -> buf1
    compute(As0, Bs0);
    __syncthreads();                 // drain buf1 prefetch
    stage(As0, Bs0, 2 * i2 + 2);     // -> buf0
    compute(As1, Bs1);
  }
  // tail: tiles KITERS-2 (buf0) and KITERS-1 (buf1)
  __syncthreads();
  stage(As1, Bs1, KITERS - 1);
  compute(As0, Bs0);
  __syncthreads();
  compute(As1, Bs1);

  // ---- epilogue: per-row (max, sumexp) over this block's 128 columns ----
  const int colBase = bn * 128 + waveN * 64;
  float bvals[4];
#pragma unroll
  for (int ni = 0; ni < 4; ++ni) bvals[ni] = bias[colBase + ni * 16 + c];

#pragma unroll
  for (int mi = 0; mi < 4; ++mi) {
    const int rowBase = bm * 128 + waveM * 64 + mi * 16 + q * 4;
#pragma unroll
    for (int reg = 0; reg < 4; ++reg) {
      const int grow = rowBase + reg;
      const int t = tgt[grow];
      float v[4];
      float mloc = -3.4e38f;
#pragma unroll
      for (int ni = 0; ni < 4; ++ni) {
        v[ni] = acc[mi][ni][reg] + bvals[ni];
        mloc = fmaxf(mloc, v[ni]);
        const int gn = colBase + ni * 16 + c;
        if (gn == t) tlogit[grow] = v[ni];  // exactly one lane/block matches
      }
#pragma unroll
      for (int off = 1; off < 16; off <<= 1) mloc = fmaxf(mloc, __shfl_xor(mloc, off));
      float sloc = 0.f;
#pragma unroll
      for (int ni = 0; ni < 4; ++ni) sloc += __expf(v[ni] - mloc);
#pragma unroll
      for (int off = 1; off < 16; off <<= 1) sloc += __shfl_xor(sloc, off);
      if (c == 0) {
        const int lrow = waveM * 64 + mi * 16 + q * 4 + reg;
        red_m[waveN][lrow] = mloc;
        red_s[waveN][lrow] = sloc;
      }
    }
  }
  __syncthreads();
  if (tid < 128) {
    const float m0 = red_m[0][tid], m1 = red_m[1][tid];
    const float s0 = red_s[0][tid], s1 = red_s[1][tid];
    const float mx = fmaxf(m0, m1);
    const float ss = s0 * __expf(m0 - mx) + s1 * __expf(m1 - mx);
    const int grow = bm * 128 + tid;
    m_part[(size_t)grow * NB + bn] = mx;
    s_part[(size_t)grow * NB + bn] = ss;
  }
}

// ---------------- combine per-row partials -> per-token logp ----------------
__global__ __launch_bounds__(256)
void combine_rows(const float* __restrict__ m_part, const float* __restrict__ s_part,
                  const float* __restrict__ tlogit, const int* __restrict__ tgt,
                  float* __restrict__ logp) {
  const int row = blockIdx.x * 4 + (threadIdx.x >> 6);
  const int lane = threadIdx.x & 63;
  const float* mrow = m_part + (size_t)row * NB;
  const float* srow = s_part + (size_t)row * NB;
  float mv[4], sv[4];
  int cnt = 0;
  float mx = -3.4e38f;
  for (int cc = lane; cc < NB; cc += 64) {
    mv[cnt] = mrow[cc]; sv[cnt] = srow[cc];
    mx = fmaxf(mx, mv[cnt]); ++cnt;
  }
#pragma unroll
  for (int off = 32; off >= 1; off >>= 1) mx = fmaxf(mx, __shfl_xor(mx, off));
  float s = 0.f;
  for (int i = 0; i < cnt; ++i) s += sv[i] * __expf(mv[i] - mx);
#pragma unroll
  for (int off = 32; off >= 1; off >>= 1) s += __shfl_xor(s, off);
  if (lane == 0) {
    const int t = tgt[row];
    logp[row] = (t == IGNORE) ? 0.f : (tlogit[row] - mx - logf(s));
  }
}

// ---------------- per-sequence average + SimPO loss ----------------
__global__ void finalize(const float* __restrict__ logp, const int* __restrict__ tgt,
                         float* __restrict__ out) {
  __shared__ float avg[8];
  const int w = threadIdx.x >> 6;     // 8 waves, one per sequence
  const int lane = threadIdx.x & 63;
  float s = 0.f, cnt = 0.f;
  for (int i = lane; i < Tt; i += 64) {
    const int idx = w * Tt + i;
    s += logp[idx];
    cnt += (tgt[idx] != IGNORE) ? 1.f : 0.f;
  }
#pragma unroll
  for (int off = 32; off >= 1; off >>= 1) {
    s += __shfl_xor(s, off);
    cnt += __shfl_xor(cnt, off);
  }
  if (lane == 0) avg[w] = s / fmaxf(cnt, 1.f);
  __syncthreads();
  if (threadIdx.x == 0) {
    float loss = 0.f;
#pragma unroll
    for (int p = 0; p < 4; ++p) {
      const float d = 0.1f * (avg[p] - avg[p + 4]) - 0.5f;
      const float nl = (d > 0.f) ? log1pf(expf(-d)) : (-d + log1pf(expf(d)));
      loss += nl;
    }
    out[0] = loss * 0.25f;  // / n_pairs
  }
}

extern "C" void kernel_launch(void* const* d_in, const int* in_sizes, int n_in,
                              void* d_out, int out_size, void* d_ws, size_t ws_size,
                              hipStream_t stream) {
  const float* Wf   = (const float*)d_in[0];  // lin_weight (V,H)
  const float* Xf   = (const float*)d_in[1];  // _input (B,T,H)
  const int*   tgt  = (const int*)d_in[2];    // target (B,T)
  const float* bias = (const float*)d_in[3];  // bias (V,)
  float* out = (float*)d_out;

  char* ws = (char*)d_ws;
  size_t off = 0;
  auto alloc = [&](size_t bytes) {
    void* p = ws + off;
    off += (bytes + 255) & ~(size_t)255;
    return p;
  };
  unsigned short* Xbf = (unsigned short*)alloc((size_t)M * K * 2);
  unsigned short* Wbf = (unsigned short*)alloc((size_t)N * K * 2);
  float* m_part = (float*)alloc((size_t)M * NB * 4);
  float* s_part = (float*)alloc((size_t)M * NB * 4);
  float* tlog   = (float*)alloc((size_t)M * 4);
  float* logp   = (float*)alloc((size_t)M * 4);

  cast_bf16_kernel<<<2048, 256, 0, stream>>>(Xf, Xbf, M * K / 4);
  cast_bf16_kernel<<<8192, 256, 0, stream>>>(Wf, Wbf, N * K / 4);

  dim3 grid(M / 128, NB);  // 32 x 250; m fastest for weight-stream L2/L3 reuse
  gemm_stats<<<grid, 256, 0, stream>>>(Xbf, Wbf, bias, tgt, m_part, s_part, tlog);

  combine_rows<<<M / 4, 256, 0, stream>>>(m_part, s_part, tlog, tgt, logp);
  finalize<<<1, 512, 0, stream>>>(logp, tgt, out);
}